// Round 14
// baseline (331.791 us; speedup 1.0000x reference)
//
#include <hip/hip_runtime.h>
#include <hip/hip_fp16.h>

#define N_NODES 100000
#define N_EDGES 1600000
#define NPB 128                                   // nodes per dst-bucket
#define NBK ((N_NODES + NPB - 1) / NPB)           // 782 buckets
#define FBLK 128                                  // fill blocks
#define EPB ((N_EDGES + FBLK - 1) / FBLK)         // 12500 edges per fill block
#define CAP 4096                                  // LDS capacity per bucket (mean 2046, sigma ~45)

typedef _Float16 h8 __attribute__((ext_vector_type(8)));
typedef float f4v __attribute__((ext_vector_type(4)));

// ---------------- pass 1: per-block bucket histograms (validated r9/r10) ----------------

__global__ void __launch_bounds__(256) hist_kernel(const int* __restrict__ dst, int* __restrict__ H) {
    __shared__ int h[NBK];
    for (int i = threadIdx.x; i < NBK; i += 256) h[i] = 0;
    __syncthreads();
    const int e0 = blockIdx.x * EPB;
    const int e1 = min(e0 + EPB, N_EDGES);
    for (int e = e0 + threadIdx.x; e < e1; e += 256) atomicAdd(&h[dst[e] >> 7], 1);
    __syncthreads();
    for (int i = threadIdx.x; i < NBK; i += 256) H[blockIdx.x * NBK + i] = h[i];
}

// ---------------- pass 2a: per-bucket column scan over the 128 blocks ----------------

__global__ void __launch_bounds__(256) colscan_kernel(int* __restrict__ H, int* __restrict__ btot) {
    const int t = blockIdx.x * 256 + threadIdx.x;
    if (t >= NBK) return;
    int run = 0;
    for (int k = 0; k < FBLK; ++k) {
        int idx = k * NBK + t;
        int h = H[idx];
        H[idx] = run;
        run += h;
    }
    btot[t] = run;
}

// ---------------- pass 2b: scan bucket totals -> bucket bases + bptr ----------------

__global__ void __launch_bounds__(1024) bucketscan_kernel(const int* __restrict__ btot,
                                                          int* __restrict__ bbase, int* __restrict__ bptr) {
    __shared__ int sh[1024];
    const int t = threadIdx.x;
    int v = (t < NBK) ? btot[t] : 0;
    sh[t] = v;
    __syncthreads();
    for (int off = 1; off < 1024; off <<= 1) {
        int u = (t >= off) ? sh[t - off] : 0;
        __syncthreads();
        sh[t] += u;
        __syncthreads();
    }
    if (t < NBK) { int e = sh[t] - v; bbase[t] = e; bptr[t] = e; }
    if (t == 0) bptr[NBK] = N_EDGES;
}

// ---------------- pass 3: bin edges by bucket (LDS cursors) ----------------

__global__ void __launch_bounds__(256) binfill_kernel(const int* __restrict__ src, const int* __restrict__ dst,
                                                      const int* __restrict__ H, const int* __restrict__ bbase,
                                                      int* __restrict__ tmp) {
    __shared__ int cur[NBK];
    const int k = blockIdx.x;
    for (int i = threadIdx.x; i < NBK; i += 256) cur[i] = H[k * NBK + i] + bbase[i];
    __syncthreads();
    const int e0 = k * EPB;
    const int e1 = min(e0 + EPB, N_EDGES);
    for (int e = e0 + threadIdx.x; e < e1; e += 256) {
        int s = src[e];
        int d = dst[e];
        int pos = atomicAdd(&cur[d >> 7], 1);
        tmp[pos] = s | ((d & (NPB - 1)) << 20);
    }
}

// ---------------- pass 4: per-bucket count/scan/rowptr/dis + LDS sort -> esrc ----------------

__global__ void __launch_bounds__(256) bucketfin_kernel(const int* __restrict__ tmp, const int* __restrict__ bptr,
                                                        int* __restrict__ esrc, int* __restrict__ rowptr,
                                                        float* __restrict__ dis, int n) {
    __shared__ int buf[CAP];
    __shared__ int cnt[NPB];
    __shared__ int sc[NPB];
    __shared__ int rp[NPB];
    __shared__ int fillc[NPB];
    const int b = blockIdx.x;
    const int d0 = b * NPB;
    const int nd = min(NPB, n - d0);
    const int base = bptr[b], end = bptr[b + 1];
    const int count = end - base;
    const int tid = threadIdx.x;

    for (int i = tid; i < NPB; i += 256) { cnt[i] = 0; fillc[i] = 0; }
    __syncthreads();
    for (int e = base + tid; e < end; e += 256) atomicAdd(&cnt[tmp[e] >> 20], 1);
    __syncthreads();

    if (tid < NPB) sc[tid] = cnt[tid];
    __syncthreads();
    for (int off = 1; off < NPB; off <<= 1) {
        int v = (tid < NPB && tid >= off) ? sc[tid - off] : 0;
        __syncthreads();
        if (tid < NPB) sc[tid] += v;
        __syncthreads();
    }
    if (tid < NPB) {
        int excl = sc[tid] - cnt[tid];
        rp[tid] = excl;
        if (tid < nd) {
            rowptr[d0 + tid] = base + excl;
            dis[d0 + tid] = rsqrtf((float)cnt[tid] + 1.0f);
        }
    }
    if (b == NBK - 1 && tid == 0) rowptr[n] = N_EDGES;
    __syncthreads();

    if (count <= CAP) {
        for (int t = base + tid; t < end; t += 256) {
            int w = tmp[t];
            int ld = w >> 20;
            int pos = rp[ld] + atomicAdd(&fillc[ld], 1);
            buf[pos] = w & 0xFFFFF;
        }
        __syncthreads();
        for (int t = tid; t < count; t += 256) esrc[base + t] = buf[t];
    } else {
        for (int t = base + tid; t < end; t += 256) {
            int w = tmp[t];
            int ld = w >> 20;
            int pos = rp[ld] + atomicAdd(&fillc[ld], 1);
            esrc[base + pos] = w & 0xFFFFF;
        }
    }
}

// ---------------- weight transposes -> fp16 W^T ----------------

__global__ void transpose_all_kernel(const float* __restrict__ W0, const float* __restrict__ W1,
                                     const float* __restrict__ W2, __half* __restrict__ wt0,
                                     __half* __restrict__ wt1, __half* __restrict__ wt2) {
    int i = blockIdx.x * blockDim.x + threadIdx.x;
    if (i < 8192)       { int k = i / 64, c = i % 64;                 wt0[c * 128 + k] = __float2half(W0[i]); }
    else if (i < 12288) { int j = i - 8192;  int k = j / 64, c = j % 64; wt1[c * 64 + k] = __float2half(W1[j]); }
    else if (i < 14336) { int j = i - 12288; int k = j / 32, c = j % 32; wt2[c * 64 + k] = __float2half(W2[j]); }
}

// ---------------- MFMA GEMM: ys[n,DOUT] = fp16(dis[row] * (x[n,DIN] @ W)) ----------------
// TIN = float (layer 0) or __half (layers 1,2). 64 rows/block, 4 waves, NT=DOUT/16 frags.
// A-frag: A[m=lane&15][k=quad*8+j]; B-frag: B[k=quad*8+j][n=lane&15] (wt16 = W^T fp16);
// C/D: col=lane&15, row=quad*4+reg. Epilogue repacks through LDS for coalesced int4 stores.

template <typename TIN, int DIN, int DOUT>
__global__ void __launch_bounds__(256) gemm_kernel(const TIN* __restrict__ x,
                                                   const __half* __restrict__ wt16,
                                                   const float* __restrict__ dis,
                                                   __half* __restrict__ ys, int n) {
    constexpr int WS = DIN + 8;          // half-element stride (16B-aligned, 2-way banks = free)
    constexpr int NT = DOUT / 16;
    constexpr int KC = DIN / 32;

    __shared__ _Float16 xls[64 * WS];
    __shared__ _Float16 wls[DOUT * WS];

    const int tid  = threadIdx.x;
    const int row0 = blockIdx.x * 64;

    // stage W (fp16, 16B chunks)
    for (int i = tid; i < DOUT * DIN / 8; i += 256) {
        int c = (i * 8) / DIN, k = (i * 8) % DIN;
        *(int4*)&wls[c * WS + k] = *(const int4*)&wt16[c * DIN + k];
    }
    // stage x
    if constexpr (sizeof(TIN) == 4) {            // fp32 -> fp16 convert
        for (int i = tid; i < 64 * DIN / 4; i += 256) {
            int r = (i * 4) / DIN, k = (i * 4) % DIN;
            float4 v = make_float4(0.f, 0.f, 0.f, 0.f);
            if (row0 + r < n) v = *(const float4*)&x[(long)(row0 + r) * DIN + k];
            _Float16 h[4] = {(_Float16)v.x, (_Float16)v.y, (_Float16)v.z, (_Float16)v.w};
            *(int2*)&xls[r * WS + k] = *(int2*)h;
        }
    } else {                                      // fp16 direct 16B copy
        for (int i = tid; i < 64 * DIN / 8; i += 256) {
            int r = (i * 8) / DIN, k = (i * 8) % DIN;
            int4 v = make_int4(0, 0, 0, 0);
            if (row0 + r < n) v = *(const int4*)&x[(long)(row0 + r) * DIN + k];
            *(int4*)&xls[r * WS + k] = v;
        }
    }
    __syncthreads();

    const int wave = tid >> 6;
    const int lane = tid & 63;
    const int m16  = lane & 15;
    const int quad = lane >> 4;

    f4v acc[NT];
#pragma unroll
    for (int t = 0; t < NT; ++t) acc[t] = (f4v){0.f, 0.f, 0.f, 0.f};

    const int arow = wave * 16 + m16;
#pragma unroll
    for (int kc = 0; kc < KC; ++kc) {
        h8 a = *(const h8*)&xls[arow * WS + kc * 32 + quad * 8];
#pragma unroll
        for (int t = 0; t < NT; ++t) {
            h8 b = *(const h8*)&wls[(t * 16 + m16) * WS + kc * 32 + quad * 8];
            acc[t] = __builtin_amdgcn_mfma_f32_16x16x32_f16(a, b, acc[t], 0, 0, 0);
        }
    }

    // epilogue: fold dis, repack via LDS (reuse xls), coalesced int4 stores
    float dsv[4];
    int   lrow[4];
#pragma unroll
    for (int reg = 0; reg < 4; ++reg) {
        lrow[reg] = wave * 16 + quad * 4 + reg;
        int grow  = row0 + lrow[reg];
        dsv[reg]  = (grow < n) ? dis[grow] : 0.f;
    }
    __syncthreads();
    _Float16* stage = xls;
#pragma unroll
    for (int t = 0; t < NT; ++t) {
#pragma unroll
        for (int reg = 0; reg < 4; ++reg)
            stage[lrow[reg] * DOUT + t * 16 + m16] = (_Float16)(acc[t][reg] * dsv[reg]);
    }
    __syncthreads();
    for (int i = tid; i < 64 * DOUT / 8; i += 256) {
        int off = i * 8;
        int r = off / DOUT;
        if (row0 + r < n)
            *(int4*)&ys[(long)row0 * DOUT + off] = *(int4*)&stage[off];
    }
}

// ---------------- gather DOUT=64: 2 nodes/wave, unroll 8, fp16 act out (nontemporal) ----------------
// out[d] = fp16( dis[d] * (ys[d] + sum_edges ys[s]) + b ), ReLU

__global__ void gather2h_kernel(const int* __restrict__ rowptr, const int* __restrict__ esrc,
                                const __half* __restrict__ ys, const float* __restrict__ dis,
                                const float* __restrict__ b, __half* __restrict__ out, int n) {
    const int node = blockIdx.x * 8 + (threadIdx.x >> 5);
    const int c = (threadIdx.x & 31) * 2;
    if (node >= n) return;

    float2 yv = __half22float2(*(const __half2*)&ys[(long)node * 64 + c]);
    float ax = yv.x, ay = yv.y;   // self term (ys already dis-scaled)

    int k = rowptr[node];
    const int end = rowptr[node + 1];
    for (; k + 8 <= end; k += 8) {
        int u0 = __builtin_nontemporal_load(&esrc[k]);
        int u1 = __builtin_nontemporal_load(&esrc[k + 1]);
        int u2 = __builtin_nontemporal_load(&esrc[k + 2]);
        int u3 = __builtin_nontemporal_load(&esrc[k + 3]);
        int u4 = __builtin_nontemporal_load(&esrc[k + 4]);
        int u5 = __builtin_nontemporal_load(&esrc[k + 5]);
        int u6 = __builtin_nontemporal_load(&esrc[k + 6]);
        int u7 = __builtin_nontemporal_load(&esrc[k + 7]);
        float2 v0 = __half22float2(*(const __half2*)&ys[(long)u0 * 64 + c]);
        float2 v1 = __half22float2(*(const __half2*)&ys[(long)u1 * 64 + c]);
        float2 v2 = __half22float2(*(const __half2*)&ys[(long)u2 * 64 + c]);
        float2 v3 = __half22float2(*(const __half2*)&ys[(long)u3 * 64 + c]);
        float2 v4 = __half22float2(*(const __half2*)&ys[(long)u4 * 64 + c]);
        float2 v5 = __half22float2(*(const __half2*)&ys[(long)u5 * 64 + c]);
        float2 v6 = __half22float2(*(const __half2*)&ys[(long)u6 * 64 + c]);
        float2 v7 = __half22float2(*(const __half2*)&ys[(long)u7 * 64 + c]);
        ax += v0.x; ay += v0.y;
        ax += v1.x; ay += v1.y;
        ax += v2.x; ay += v2.y;
        ax += v3.x; ay += v3.y;
        ax += v4.x; ay += v4.y;
        ax += v5.x; ay += v5.y;
        ax += v6.x; ay += v6.y;
        ax += v7.x; ay += v7.y;
    }
    for (; k < end; ++k) {
        int u = __builtin_nontemporal_load(&esrc[k]);
        float2 v = __half22float2(*(const __half2*)&ys[(long)u * 64 + c]);
        ax += v.x; ay += v.y;
    }

    const float di = dis[node];
    ax = fmaxf(ax * di + b[c], 0.0f);
    ay = fmaxf(ay * di + b[c + 1], 0.0f);
    __half2 hv = __halves2half2(__float2half(ax), __float2half(ay));
    __builtin_nontemporal_store(*(int*)&hv, (int*)&out[(long)node * 64 + c]);
}

// ---------------- gather DOUT=32: 4 nodes/wave, unroll 8, fp32 out (nontemporal) ----------------

__global__ void gather4h_kernel(const int* __restrict__ rowptr, const int* __restrict__ esrc,
                                const __half* __restrict__ ys, const float* __restrict__ dis,
                                const float* __restrict__ b, float* __restrict__ out, int n) {
    const int node = blockIdx.x * 16 + (threadIdx.x >> 4);
    const int c = (threadIdx.x & 15) * 2;
    if (node >= n) return;

    float2 yv = __half22float2(*(const __half2*)&ys[(long)node * 32 + c]);
    float ax = yv.x, ay = yv.y;

    int k = rowptr[node];
    const int end = rowptr[node + 1];
    for (; k + 8 <= end; k += 8) {
        int u0 = __builtin_nontemporal_load(&esrc[k]);
        int u1 = __builtin_nontemporal_load(&esrc[k + 1]);
        int u2 = __builtin_nontemporal_load(&esrc[k + 2]);
        int u3 = __builtin_nontemporal_load(&esrc[k + 3]);
        int u4 = __builtin_nontemporal_load(&esrc[k + 4]);
        int u5 = __builtin_nontemporal_load(&esrc[k + 5]);
        int u6 = __builtin_nontemporal_load(&esrc[k + 6]);
        int u7 = __builtin_nontemporal_load(&esrc[k + 7]);
        float2 v0 = __half22float2(*(const __half2*)&ys[(long)u0 * 32 + c]);
        float2 v1 = __half22float2(*(const __half2*)&ys[(long)u1 * 32 + c]);
        float2 v2 = __half22float2(*(const __half2*)&ys[(long)u2 * 32 + c]);
        float2 v3 = __half22float2(*(const __half2*)&ys[(long)u3 * 32 + c]);
        float2 v4 = __half22float2(*(const __half2*)&ys[(long)u4 * 32 + c]);
        float2 v5 = __half22float2(*(const __half2*)&ys[(long)u5 * 32 + c]);
        float2 v6 = __half22float2(*(const __half2*)&ys[(long)u6 * 32 + c]);
        float2 v7 = __half22float2(*(const __half2*)&ys[(long)u7 * 32 + c]);
        ax += v0.x; ay += v0.y;
        ax += v1.x; ay += v1.y;
        ax += v2.x; ay += v2.y;
        ax += v3.x; ay += v3.y;
        ax += v4.x; ay += v4.y;
        ax += v5.x; ay += v5.y;
        ax += v6.x; ay += v6.y;
        ax += v7.x; ay += v7.y;
    }
    for (; k < end; ++k) {
        int u = __builtin_nontemporal_load(&esrc[k]);
        float2 v = __half22float2(*(const __half2*)&ys[(long)u * 32 + c]);
        ax += v.x; ay += v.y;
    }

    const float di = dis[node];
    ax = ax * di + b[c];
    ay = ay * di + b[c + 1];
    __builtin_nontemporal_store(ax, &out[(long)node * 32 + c]);
    __builtin_nontemporal_store(ay, &out[(long)node * 32 + c + 1]);
}

// ---------------- launch ----------------

extern "C" void kernel_launch(void* const* d_in, const int* in_sizes, int n_in,
                              void* d_out, int out_size, void* d_ws, size_t ws_size,
                              hipStream_t stream) {
    const float* features = (const float*)d_in[0];
    const int*   ei       = (const int*)d_in[1];
    const float* W0 = (const float*)d_in[2];
    const float* b0 = (const float*)d_in[3];
    const float* W1 = (const float*)d_in[4];
    const float* b1 = (const float*)d_in[5];
    const float* W2 = (const float*)d_in[6];
    const float* b2 = (const float*)d_in[7];

    const int* src = ei;             // edge_index[0]
    const int* dst = ei + N_EDGES;   // edge_index[1]

    const int n = N_NODES;

    // workspace layout (int slots)
    int*    H      = (int*)d_ws;                       // [0, 131072)
    int*    btot   = (int*)d_ws + 131072;              // [131072, 132096)
    int*    bbase  = (int*)d_ws + 132096;              // [132096, 133120)
    int*    bptr   = (int*)d_ws + 133120;              // [133120, 135168)
    float*  dis    = (float*)d_ws + 135168;            // [135168, 266240)
    int*    rowptr = (int*)d_ws + 266240;              // [266240, 397312)  n+1 fits
    int*    tmp    = (int*)d_ws + 397312;              // E ints
    int*    esrc   = (int*)d_ws + 1997312;             // E ints
    __half* ys     = (__half*)((int*)d_ws + 3597312);  // N*64 halves = 3.2M ints
    __half* act    = (__half*)((int*)d_ws + 6797312);  // N*64 halves = 3.2M ints
    __half* wt0    = (__half*)((int*)d_ws + 13197312); // 8192 halves
    __half* wt1    = (__half*)((int*)d_ws + 13201408); // 4096 halves
    __half* wt2    = (__half*)((int*)d_ws + 13203456); // 2048 halves
    float*  outf   = (float*)d_out;                    // N*32 fp32

    // ---- contention-free CSR build + transposes ----
    hist_kernel<<<FBLK, 256, 0, stream>>>(dst, H);
    colscan_kernel<<<(NBK + 255) / 256, 256, 0, stream>>>(H, btot);
    bucketscan_kernel<<<1, 1024, 0, stream>>>(btot, bbase, bptr);
    binfill_kernel<<<FBLK, 256, 0, stream>>>(src, dst, H, bbase, tmp);
    bucketfin_kernel<<<NBK, 256, 0, stream>>>(tmp, bptr, esrc, rowptr, dis, n);
    transpose_all_kernel<<<56, 256, 0, stream>>>(W0, W1, W2, wt0, wt1, wt2);

    // ---- layer 0: 128 -> 64, ReLU ----
    gemm_kernel<float, 128, 64><<<(n + 63) / 64, 256, 0, stream>>>(features, wt0, dis, ys, n);
    gather2h_kernel<<<(n + 7) / 8, 256, 0, stream>>>(rowptr, esrc, ys, dis, b0, act, n);

    // ---- layer 1: 64 -> 64, ReLU ----
    gemm_kernel<__half, 64, 64><<<(n + 63) / 64, 256, 0, stream>>>(act, wt1, dis, ys, n);
    gather2h_kernel<<<(n + 7) / 8, 256, 0, stream>>>(rowptr, esrc, ys, dis, b1, act, n);

    // ---- layer 2: 64 -> 32, no ReLU ----
    gemm_kernel<__half, 64, 32><<<(n + 63) / 64, 256, 0, stream>>>(act, wt2, dis, ys, n);
    gather4h_kernel<<<(n + 15) / 16, 256, 0, stream>>>(rowptr, esrc, ys, dis, b2, outf, n);
}

// Round 15
// 304.427 us; speedup vs baseline: 1.0899x; 1.0899x over previous
//
#include <hip/hip_runtime.h>
#include <hip/hip_fp16.h>

#define N_NODES 100000
#define N_EDGES 1600000
#define NPB 128                                   // nodes per dst-bucket
#define NBK ((N_NODES + NPB - 1) / NPB)           // 782 buckets
#define FBLK 128                                  // fill blocks
#define EPB ((N_EDGES + FBLK - 1) / FBLK)         // 12500 edges per fill block
#define CAP 4096                                  // LDS capacity per bucket (mean 2046, sigma ~45)

typedef _Float16 h8 __attribute__((ext_vector_type(8)));
typedef float f4v __attribute__((ext_vector_type(4)));

// ---------------- pass 1: per-block bucket histograms (validated r9/r10) ----------------

__global__ void __launch_bounds__(256) hist_kernel(const int* __restrict__ dst, int* __restrict__ H) {
    __shared__ int h[NBK];
    for (int i = threadIdx.x; i < NBK; i += 256) h[i] = 0;
    __syncthreads();
    const int e0 = blockIdx.x * EPB;
    const int e1 = min(e0 + EPB, N_EDGES);
    for (int e = e0 + threadIdx.x; e < e1; e += 256) atomicAdd(&h[dst[e] >> 7], 1);
    __syncthreads();
    for (int i = threadIdx.x; i < NBK; i += 256) H[blockIdx.x * NBK + i] = h[i];
}

// ---------------- pass 2a: per-bucket column scan over the 128 blocks ----------------

__global__ void __launch_bounds__(256) colscan_kernel(int* __restrict__ H, int* __restrict__ btot) {
    const int t = blockIdx.x * 256 + threadIdx.x;
    if (t >= NBK) return;
    int run = 0;
    for (int k = 0; k < FBLK; ++k) {
        int idx = k * NBK + t;
        int h = H[idx];
        H[idx] = run;
        run += h;
    }
    btot[t] = run;
}

// ---------------- pass 2b: scan bucket totals -> bucket bases + bptr ----------------

__global__ void __launch_bounds__(1024) bucketscan_kernel(const int* __restrict__ btot,
                                                          int* __restrict__ bbase, int* __restrict__ bptr) {
    __shared__ int sh[1024];
    const int t = threadIdx.x;
    int v = (t < NBK) ? btot[t] : 0;
    sh[t] = v;
    __syncthreads();
    for (int off = 1; off < 1024; off <<= 1) {
        int u = (t >= off) ? sh[t - off] : 0;
        __syncthreads();
        sh[t] += u;
        __syncthreads();
    }
    if (t < NBK) { int e = sh[t] - v; bbase[t] = e; bptr[t] = e; }
    if (t == 0) bptr[NBK] = N_EDGES;
}

// ---------------- pass 3: bin edges by bucket (LDS cursors) ----------------

__global__ void __launch_bounds__(256) binfill_kernel(const int* __restrict__ src, const int* __restrict__ dst,
                                                      const int* __restrict__ H, const int* __restrict__ bbase,
                                                      int* __restrict__ tmp) {
    __shared__ int cur[NBK];
    const int k = blockIdx.x;
    for (int i = threadIdx.x; i < NBK; i += 256) cur[i] = H[k * NBK + i] + bbase[i];
    __syncthreads();
    const int e0 = k * EPB;
    const int e1 = min(e0 + EPB, N_EDGES);
    for (int e = e0 + threadIdx.x; e < e1; e += 256) {
        int s = src[e];
        int d = dst[e];
        int pos = atomicAdd(&cur[d >> 7], 1);
        tmp[pos] = s | ((d & (NPB - 1)) << 20);
    }
}

// ---------------- pass 4: per-bucket count/scan/rowptr/dis + LDS sort -> esrc ----------------

__global__ void __launch_bounds__(256) bucketfin_kernel(const int* __restrict__ tmp, const int* __restrict__ bptr,
                                                        int* __restrict__ esrc, int* __restrict__ rowptr,
                                                        float* __restrict__ dis, int n) {
    __shared__ int buf[CAP];
    __shared__ int cnt[NPB];
    __shared__ int sc[NPB];
    __shared__ int rp[NPB];
    __shared__ int fillc[NPB];
    const int b = blockIdx.x;
    const int d0 = b * NPB;
    const int nd = min(NPB, n - d0);
    const int base = bptr[b], end = bptr[b + 1];
    const int count = end - base;
    const int tid = threadIdx.x;

    for (int i = tid; i < NPB; i += 256) { cnt[i] = 0; fillc[i] = 0; }
    __syncthreads();
    for (int e = base + tid; e < end; e += 256) atomicAdd(&cnt[tmp[e] >> 20], 1);
    __syncthreads();

    if (tid < NPB) sc[tid] = cnt[tid];
    __syncthreads();
    for (int off = 1; off < NPB; off <<= 1) {
        int v = (tid < NPB && tid >= off) ? sc[tid - off] : 0;
        __syncthreads();
        if (tid < NPB) sc[tid] += v;
        __syncthreads();
    }
    if (tid < NPB) {
        int excl = sc[tid] - cnt[tid];
        rp[tid] = excl;
        if (tid < nd) {
            rowptr[d0 + tid] = base + excl;
            dis[d0 + tid] = rsqrtf((float)cnt[tid] + 1.0f);
        }
    }
    if (b == NBK - 1 && tid == 0) rowptr[n] = N_EDGES;
    __syncthreads();

    if (count <= CAP) {
        for (int t = base + tid; t < end; t += 256) {
            int w = tmp[t];
            int ld = w >> 20;
            int pos = rp[ld] + atomicAdd(&fillc[ld], 1);
            buf[pos] = w & 0xFFFFF;
        }
        __syncthreads();
        for (int t = tid; t < count; t += 256) esrc[base + t] = buf[t];
    } else {
        for (int t = base + tid; t < end; t += 256) {
            int w = tmp[t];
            int ld = w >> 20;
            int pos = rp[ld] + atomicAdd(&fillc[ld], 1);
            esrc[base + pos] = w & 0xFFFFF;
        }
    }
}

// ---------------- weight transposes -> fp16 W^T ----------------

__global__ void transpose_all_kernel(const float* __restrict__ W0, const float* __restrict__ W1,
                                     const float* __restrict__ W2, __half* __restrict__ wt0,
                                     __half* __restrict__ wt1, __half* __restrict__ wt2) {
    int i = blockIdx.x * blockDim.x + threadIdx.x;
    if (i < 8192)       { int k = i / 64, c = i % 64;                 wt0[c * 128 + k] = __float2half(W0[i]); }
    else if (i < 12288) { int j = i - 8192;  int k = j / 64, c = j % 64; wt1[c * 64 + k] = __float2half(W1[j]); }
    else if (i < 14336) { int j = i - 12288; int k = j / 32, c = j % 32; wt2[c * 64 + k] = __float2half(W2[j]); }
}

// ---------------- MFMA GEMM: ys[n,DOUT] = fp16(dis[row] * (x[n,DIN] @ W)) ----------------
// TIN = float (layer 0) or __half (layers 1,2). 64 rows/block, 4 waves, NT=DOUT/16 frags.
// A-frag: A[m=lane&15][k=quad*8+j]; B-frag: B[k=quad*8+j][n=lane&15] (wt16 = W^T fp16);
// C/D: col=lane&15, row=quad*4+reg. Epilogue repacks through LDS for coalesced int4 stores.

template <typename TIN, int DIN, int DOUT>
__global__ void __launch_bounds__(256) gemm_kernel(const TIN* __restrict__ x,
                                                   const __half* __restrict__ wt16,
                                                   const float* __restrict__ dis,
                                                   __half* __restrict__ ys, int n) {
    constexpr int WS = DIN + 8;          // half-element stride (16B-aligned, 2-way banks = free)
    constexpr int NT = DOUT / 16;
    constexpr int KC = DIN / 32;

    __shared__ _Float16 xls[64 * WS];
    __shared__ _Float16 wls[DOUT * WS];

    const int tid  = threadIdx.x;
    const int row0 = blockIdx.x * 64;

    // stage W (fp16, 16B chunks)
    for (int i = tid; i < DOUT * DIN / 8; i += 256) {
        int c = (i * 8) / DIN, k = (i * 8) % DIN;
        *(int4*)&wls[c * WS + k] = *(const int4*)&wt16[c * DIN + k];
    }
    // stage x
    if constexpr (sizeof(TIN) == 4) {            // fp32 -> fp16 convert
        for (int i = tid; i < 64 * DIN / 4; i += 256) {
            int r = (i * 4) / DIN, k = (i * 4) % DIN;
            float4 v = make_float4(0.f, 0.f, 0.f, 0.f);
            if (row0 + r < n) v = *(const float4*)&x[(long)(row0 + r) * DIN + k];
            _Float16 h[4] = {(_Float16)v.x, (_Float16)v.y, (_Float16)v.z, (_Float16)v.w};
            *(int2*)&xls[r * WS + k] = *(int2*)h;
        }
    } else {                                      // fp16 direct 16B copy
        for (int i = tid; i < 64 * DIN / 8; i += 256) {
            int r = (i * 8) / DIN, k = (i * 8) % DIN;
            int4 v = make_int4(0, 0, 0, 0);
            if (row0 + r < n) v = *(const int4*)&x[(long)(row0 + r) * DIN + k];
            *(int4*)&xls[r * WS + k] = v;
        }
    }
    __syncthreads();

    const int wave = tid >> 6;
    const int lane = tid & 63;
    const int m16  = lane & 15;
    const int quad = lane >> 4;

    f4v acc[NT];
#pragma unroll
    for (int t = 0; t < NT; ++t) acc[t] = (f4v){0.f, 0.f, 0.f, 0.f};

    const int arow = wave * 16 + m16;
#pragma unroll
    for (int kc = 0; kc < KC; ++kc) {
        h8 a = *(const h8*)&xls[arow * WS + kc * 32 + quad * 8];
#pragma unroll
        for (int t = 0; t < NT; ++t) {
            h8 b = *(const h8*)&wls[(t * 16 + m16) * WS + kc * 32 + quad * 8];
            acc[t] = __builtin_amdgcn_mfma_f32_16x16x32_f16(a, b, acc[t], 0, 0, 0);
        }
    }

    // epilogue: fold dis, repack via LDS (reuse xls), coalesced int4 stores
    float dsv[4];
    int   lrow[4];
#pragma unroll
    for (int reg = 0; reg < 4; ++reg) {
        lrow[reg] = wave * 16 + quad * 4 + reg;
        int grow  = row0 + lrow[reg];
        dsv[reg]  = (grow < n) ? dis[grow] : 0.f;
    }
    __syncthreads();
    _Float16* stage = xls;
#pragma unroll
    for (int t = 0; t < NT; ++t) {
#pragma unroll
        for (int reg = 0; reg < 4; ++reg)
            stage[lrow[reg] * DOUT + t * 16 + m16] = (_Float16)(acc[t][reg] * dsv[reg]);
    }
    __syncthreads();
    for (int i = tid; i < 64 * DOUT / 8; i += 256) {
        int off = i * 8;
        int r = off / DOUT;
        if (row0 + r < n)
            *(int4*)&ys[(long)row0 * DOUT + off] = *(int4*)&stage[off];
    }
}

// ---------------- gather DOUT=64: 2 nodes/wave, unroll 8, fp16 act out ----------------
// out[d] = fp16( relu( dis[d] * (ys[d] + sum_edges ys[s]) + b ) )

__global__ void gather2h_kernel(const int* __restrict__ rowptr, const int* __restrict__ esrc,
                                const __half* __restrict__ ys, const float* __restrict__ dis,
                                const float* __restrict__ b, __half* __restrict__ out, int n) {
    const int node = blockIdx.x * 8 + (threadIdx.x >> 5);
    const int c = (threadIdx.x & 31) * 2;
    if (node >= n) return;

    float2 yv = __half22float2(*(const __half2*)&ys[(long)node * 64 + c]);
    float ax = yv.x, ay = yv.y;   // self term (ys already dis-scaled)

    int k = rowptr[node];
    const int end = rowptr[node + 1];
    for (; k + 8 <= end; k += 8) {
        int u0 = esrc[k], u1 = esrc[k + 1], u2 = esrc[k + 2], u3 = esrc[k + 3];
        int u4 = esrc[k + 4], u5 = esrc[k + 5], u6 = esrc[k + 6], u7 = esrc[k + 7];
        float2 v0 = __half22float2(*(const __half2*)&ys[(long)u0 * 64 + c]);
        float2 v1 = __half22float2(*(const __half2*)&ys[(long)u1 * 64 + c]);
        float2 v2 = __half22float2(*(const __half2*)&ys[(long)u2 * 64 + c]);
        float2 v3 = __half22float2(*(const __half2*)&ys[(long)u3 * 64 + c]);
        float2 v4 = __half22float2(*(const __half2*)&ys[(long)u4 * 64 + c]);
        float2 v5 = __half22float2(*(const __half2*)&ys[(long)u5 * 64 + c]);
        float2 v6 = __half22float2(*(const __half2*)&ys[(long)u6 * 64 + c]);
        float2 v7 = __half22float2(*(const __half2*)&ys[(long)u7 * 64 + c]);
        ax += v0.x; ay += v0.y;
        ax += v1.x; ay += v1.y;
        ax += v2.x; ay += v2.y;
        ax += v3.x; ay += v3.y;
        ax += v4.x; ay += v4.y;
        ax += v5.x; ay += v5.y;
        ax += v6.x; ay += v6.y;
        ax += v7.x; ay += v7.y;
    }
    for (; k < end; ++k) {
        int u = esrc[k];
        float2 v = __half22float2(*(const __half2*)&ys[(long)u * 64 + c]);
        ax += v.x; ay += v.y;
    }

    const float di = dis[node];
    ax = fmaxf(ax * di + b[c], 0.0f);
    ay = fmaxf(ay * di + b[c + 1], 0.0f);
    *(__half2*)&out[(long)node * 64 + c] = __halves2half2(__float2half(ax), __float2half(ay));
}

// ---------------- gather DOUT=32: 4 nodes/wave, unroll 8, fp32 out ----------------

__global__ void gather4h_kernel(const int* __restrict__ rowptr, const int* __restrict__ esrc,
                                const __half* __restrict__ ys, const float* __restrict__ dis,
                                const float* __restrict__ b, float* __restrict__ out, int n) {
    const int node = blockIdx.x * 16 + (threadIdx.x >> 4);
    const int c = (threadIdx.x & 15) * 2;
    if (node >= n) return;

    float2 yv = __half22float2(*(const __half2*)&ys[(long)node * 32 + c]);
    float ax = yv.x, ay = yv.y;

    int k = rowptr[node];
    const int end = rowptr[node + 1];
    for (; k + 8 <= end; k += 8) {
        int u0 = esrc[k], u1 = esrc[k + 1], u2 = esrc[k + 2], u3 = esrc[k + 3];
        int u4 = esrc[k + 4], u5 = esrc[k + 5], u6 = esrc[k + 6], u7 = esrc[k + 7];
        float2 v0 = __half22float2(*(const __half2*)&ys[(long)u0 * 32 + c]);
        float2 v1 = __half22float2(*(const __half2*)&ys[(long)u1 * 32 + c]);
        float2 v2 = __half22float2(*(const __half2*)&ys[(long)u2 * 32 + c]);
        float2 v3 = __half22float2(*(const __half2*)&ys[(long)u3 * 32 + c]);
        float2 v4 = __half22float2(*(const __half2*)&ys[(long)u4 * 32 + c]);
        float2 v5 = __half22float2(*(const __half2*)&ys[(long)u5 * 32 + c]);
        float2 v6 = __half22float2(*(const __half2*)&ys[(long)u6 * 32 + c]);
        float2 v7 = __half22float2(*(const __half2*)&ys[(long)u7 * 32 + c]);
        ax += v0.x; ay += v0.y;
        ax += v1.x; ay += v1.y;
        ax += v2.x; ay += v2.y;
        ax += v3.x; ay += v3.y;
        ax += v4.x; ay += v4.y;
        ax += v5.x; ay += v5.y;
        ax += v6.x; ay += v6.y;
        ax += v7.x; ay += v7.y;
    }
    for (; k < end; ++k) {
        int u = esrc[k];
        float2 v = __half22float2(*(const __half2*)&ys[(long)u * 32 + c]);
        ax += v.x; ay += v.y;
    }

    const float di = dis[node];
    ax = ax * di + b[c];
    ay = ay * di + b[c + 1];
    *(float2*)&out[(long)node * 32 + c] = make_float2(ax, ay);
}

// ---------------- launch ----------------

extern "C" void kernel_launch(void* const* d_in, const int* in_sizes, int n_in,
                              void* d_out, int out_size, void* d_ws, size_t ws_size,
                              hipStream_t stream) {
    const float* features = (const float*)d_in[0];
    const int*   ei       = (const int*)d_in[1];
    const float* W0 = (const float*)d_in[2];
    const float* b0 = (const float*)d_in[3];
    const float* W1 = (const float*)d_in[4];
    const float* b1 = (const float*)d_in[5];
    const float* W2 = (const float*)d_in[6];
    const float* b2 = (const float*)d_in[7];

    const int* src = ei;             // edge_index[0]
    const int* dst = ei + N_EDGES;   // edge_index[1]

    const int n = N_NODES;

    // workspace layout (int slots)
    int*    H      = (int*)d_ws;                       // [0, 131072)
    int*    btot   = (int*)d_ws + 131072;              // [131072, 132096)
    int*    bbase  = (int*)d_ws + 132096;              // [132096, 133120)
    int*    bptr   = (int*)d_ws + 133120;              // [133120, 135168)
    float*  dis    = (float*)d_ws + 135168;            // [135168, 266240)
    int*    rowptr = (int*)d_ws + 266240;              // [266240, 397312)  n+1 fits
    int*    tmp    = (int*)d_ws + 397312;              // E ints
    int*    esrc   = (int*)d_ws + 1997312;             // E ints
    __half* ys     = (__half*)((int*)d_ws + 3597312);  // N*64 halves = 3.2M ints
    __half* act    = (__half*)((int*)d_ws + 6797312);  // N*64 halves = 3.2M ints
    __half* wt0    = (__half*)((int*)d_ws + 13197312); // 8192 halves
    __half* wt1    = (__half*)((int*)d_ws + 13201408); // 4096 halves
    __half* wt2    = (__half*)((int*)d_ws + 13203456); // 2048 halves
    float*  outf   = (float*)d_out;                    // N*32 fp32

    // ---- contention-free CSR build + transposes ----
    hist_kernel<<<FBLK, 256, 0, stream>>>(dst, H);
    colscan_kernel<<<(NBK + 255) / 256, 256, 0, stream>>>(H, btot);
    bucketscan_kernel<<<1, 1024, 0, stream>>>(btot, bbase, bptr);
    binfill_kernel<<<FBLK, 256, 0, stream>>>(src, dst, H, bbase, tmp);
    bucketfin_kernel<<<NBK, 256, 0, stream>>>(tmp, bptr, esrc, rowptr, dis, n);
    transpose_all_kernel<<<56, 256, 0, stream>>>(W0, W1, W2, wt0, wt1, wt2);

    // ---- layer 0: 128 -> 64, ReLU ----
    gemm_kernel<float, 128, 64><<<(n + 63) / 64, 256, 0, stream>>>(features, wt0, dis, ys, n);
    gather2h_kernel<<<(n + 7) / 8, 256, 0, stream>>>(rowptr, esrc, ys, dis, b0, act, n);

    // ---- layer 1: 64 -> 64, ReLU ----
    gemm_kernel<__half, 64, 64><<<(n + 63) / 64, 256, 0, stream>>>(act, wt1, dis, ys, n);
    gather2h_kernel<<<(n + 7) / 8, 256, 0, stream>>>(rowptr, esrc, ys, dis, b1, act, n);

    // ---- layer 2: 64 -> 32, no ReLU ----
    gemm_kernel<__half, 64, 32><<<(n + 63) / 64, 256, 0, stream>>>(act, wt2, dis, ys, n);
    gather4h_kernel<<<(n + 15) / 16, 256, 0, stream>>>(rowptr, esrc, ys, dis, b2, outf, n);
}

// Round 16
// 285.095 us; speedup vs baseline: 1.1638x; 1.0678x over previous
//
#include <hip/hip_runtime.h>
#include <hip/hip_fp16.h>

#define N_NODES 100000
#define N_EDGES 1600000
#define NPB 128                                   // nodes per dst-bucket
#define NBK ((N_NODES + NPB - 1) / NPB)           // 782 buckets
#define FBLK 128                                  // fill blocks
#define EPB ((N_EDGES + FBLK - 1) / FBLK)         // 12500 edges per fill block
#define CAP 4096                                  // LDS capacity per bucket (mean 2046, sigma ~45)

typedef _Float16 h8 __attribute__((ext_vector_type(8)));
typedef float f4v __attribute__((ext_vector_type(4)));

// ---------------- pass 1: per-block bucket histograms (validated r9/r10) ----------------

__global__ void __launch_bounds__(256) hist_kernel(const int* __restrict__ dst, int* __restrict__ H) {
    __shared__ int h[NBK];
    for (int i = threadIdx.x; i < NBK; i += 256) h[i] = 0;
    __syncthreads();
    const int e0 = blockIdx.x * EPB;
    const int e1 = min(e0 + EPB, N_EDGES);
    for (int e = e0 + threadIdx.x; e < e1; e += 256) atomicAdd(&h[dst[e] >> 7], 1);
    __syncthreads();
    for (int i = threadIdx.x; i < NBK; i += 256) H[blockIdx.x * NBK + i] = h[i];
}

// ---------------- pass 2a: per-bucket column scan over the 128 blocks ----------------

__global__ void __launch_bounds__(256) colscan_kernel(int* __restrict__ H, int* __restrict__ btot) {
    const int t = blockIdx.x * 256 + threadIdx.x;
    if (t >= NBK) return;
    int run = 0;
    for (int k = 0; k < FBLK; ++k) {
        int idx = k * NBK + t;
        int h = H[idx];
        H[idx] = run;
        run += h;
    }
    btot[t] = run;
}

// ---------------- pass 2b: scan bucket totals -> bucket bases + bptr ----------------

__global__ void __launch_bounds__(1024) bucketscan_kernel(const int* __restrict__ btot,
                                                          int* __restrict__ bbase, int* __restrict__ bptr) {
    __shared__ int sh[1024];
    const int t = threadIdx.x;
    int v = (t < NBK) ? btot[t] : 0;
    sh[t] = v;
    __syncthreads();
    for (int off = 1; off < 1024; off <<= 1) {
        int u = (t >= off) ? sh[t - off] : 0;
        __syncthreads();
        sh[t] += u;
        __syncthreads();
    }
    if (t < NBK) { int e = sh[t] - v; bbase[t] = e; bptr[t] = e; }
    if (t == 0) bptr[NBK] = N_EDGES;
}

// ---------------- pass 3: bin edges by bucket (LDS cursors) ----------------

__global__ void __launch_bounds__(256) binfill_kernel(const int* __restrict__ src, const int* __restrict__ dst,
                                                      const int* __restrict__ H, const int* __restrict__ bbase,
                                                      int* __restrict__ tmp) {
    __shared__ int cur[NBK];
    const int k = blockIdx.x;
    for (int i = threadIdx.x; i < NBK; i += 256) cur[i] = H[k * NBK + i] + bbase[i];
    __syncthreads();
    const int e0 = k * EPB;
    const int e1 = min(e0 + EPB, N_EDGES);
    for (int e = e0 + threadIdx.x; e < e1; e += 256) {
        int s = src[e];
        int d = dst[e];
        int pos = atomicAdd(&cur[d >> 7], 1);
        tmp[pos] = s | ((d & (NPB - 1)) << 20);
    }
}

// ---------------- pass 4: per-bucket count/scan/rowptr/dis + LDS sort -> esrc ----------------

__global__ void __launch_bounds__(256) bucketfin_kernel(const int* __restrict__ tmp, const int* __restrict__ bptr,
                                                        int* __restrict__ esrc, int* __restrict__ rowptr,
                                                        float* __restrict__ dis, int n) {
    __shared__ int buf[CAP];
    __shared__ int cnt[NPB];
    __shared__ int sc[NPB];
    __shared__ int rp[NPB];
    __shared__ int fillc[NPB];
    const int b = blockIdx.x;
    const int d0 = b * NPB;
    const int nd = min(NPB, n - d0);
    const int base = bptr[b], end = bptr[b + 1];
    const int count = end - base;
    const int tid = threadIdx.x;

    for (int i = tid; i < NPB; i += 256) { cnt[i] = 0; fillc[i] = 0; }
    __syncthreads();
    for (int e = base + tid; e < end; e += 256) atomicAdd(&cnt[tmp[e] >> 20], 1);
    __syncthreads();

    if (tid < NPB) sc[tid] = cnt[tid];
    __syncthreads();
    for (int off = 1; off < NPB; off <<= 1) {
        int v = (tid < NPB && tid >= off) ? sc[tid - off] : 0;
        __syncthreads();
        if (tid < NPB) sc[tid] += v;
        __syncthreads();
    }
    if (tid < NPB) {
        int excl = sc[tid] - cnt[tid];
        rp[tid] = excl;
        if (tid < nd) {
            rowptr[d0 + tid] = base + excl;
            dis[d0 + tid] = rsqrtf((float)cnt[tid] + 1.0f);
        }
    }
    if (b == NBK - 1 && tid == 0) rowptr[n] = N_EDGES;
    __syncthreads();

    if (count <= CAP) {
        for (int t = base + tid; t < end; t += 256) {
            int w = tmp[t];
            int ld = w >> 20;
            int pos = rp[ld] + atomicAdd(&fillc[ld], 1);
            buf[pos] = w & 0xFFFFF;
        }
        __syncthreads();
        for (int t = tid; t < count; t += 256) esrc[base + t] = buf[t];
    } else {
        for (int t = base + tid; t < end; t += 256) {
            int w = tmp[t];
            int ld = w >> 20;
            int pos = rp[ld] + atomicAdd(&fillc[ld], 1);
            esrc[base + pos] = w & 0xFFFFF;
        }
    }
}

// ---------------- weight transposes -> fp16 W^T ----------------

__global__ void transpose_all_kernel(const float* __restrict__ W0, const float* __restrict__ W1,
                                     const float* __restrict__ W2, __half* __restrict__ wt0,
                                     __half* __restrict__ wt1, __half* __restrict__ wt2) {
    int i = blockIdx.x * blockDim.x + threadIdx.x;
    if (i < 8192)       { int k = i / 64, c = i % 64;                 wt0[c * 128 + k] = __float2half(W0[i]); }
    else if (i < 12288) { int j = i - 8192;  int k = j / 64, c = j % 64; wt1[c * 64 + k] = __float2half(W1[j]); }
    else if (i < 14336) { int j = i - 12288; int k = j / 32, c = j % 32; wt2[c * 64 + k] = __float2half(W2[j]); }
}

// ---------------- MFMA GEMM: ys[n,DOUT] = fp16(dis[row] * (x[n,DIN] @ W)) ----------------
// TIN = float (layer 0) or __half (layers 1,2). 64 rows/block, 4 waves, NT=DOUT/16 frags.
// A-frag: A[m=lane&15][k=quad*8+j]; B-frag: B[k=quad*8+j][n=lane&15] (wt16 = W^T fp16);
// C/D: col=lane&15, row=quad*4+reg. Epilogue repacks through LDS for coalesced int4 stores.

template <typename TIN, int DIN, int DOUT>
__global__ void __launch_bounds__(256) gemm_kernel(const TIN* __restrict__ x,
                                                   const __half* __restrict__ wt16,
                                                   const float* __restrict__ dis,
                                                   __half* __restrict__ ys, int n) {
    constexpr int WS = DIN + 8;          // half-element stride (16B-aligned, 2-way banks = free)
    constexpr int NT = DOUT / 16;
    constexpr int KC = DIN / 32;

    __shared__ _Float16 xls[64 * WS];
    __shared__ _Float16 wls[DOUT * WS];

    const int tid  = threadIdx.x;
    const int row0 = blockIdx.x * 64;

    // stage W (fp16, 16B chunks)
    for (int i = tid; i < DOUT * DIN / 8; i += 256) {
        int c = (i * 8) / DIN, k = (i * 8) % DIN;
        *(int4*)&wls[c * WS + k] = *(const int4*)&wt16[c * DIN + k];
    }
    // stage x
    if constexpr (sizeof(TIN) == 4) {            // fp32 -> fp16 convert
        for (int i = tid; i < 64 * DIN / 4; i += 256) {
            int r = (i * 4) / DIN, k = (i * 4) % DIN;
            float4 v = make_float4(0.f, 0.f, 0.f, 0.f);
            if (row0 + r < n) v = *(const float4*)&x[(long)(row0 + r) * DIN + k];
            _Float16 h[4] = {(_Float16)v.x, (_Float16)v.y, (_Float16)v.z, (_Float16)v.w};
            *(int2*)&xls[r * WS + k] = *(int2*)h;
        }
    } else {                                      // fp16 direct 16B copy
        for (int i = tid; i < 64 * DIN / 8; i += 256) {
            int r = (i * 8) / DIN, k = (i * 8) % DIN;
            int4 v = make_int4(0, 0, 0, 0);
            if (row0 + r < n) v = *(const int4*)&x[(long)(row0 + r) * DIN + k];
            *(int4*)&xls[r * WS + k] = v;
        }
    }
    __syncthreads();

    const int wave = tid >> 6;
    const int lane = tid & 63;
    const int m16  = lane & 15;
    const int quad = lane >> 4;

    f4v acc[NT];
#pragma unroll
    for (int t = 0; t < NT; ++t) acc[t] = (f4v){0.f, 0.f, 0.f, 0.f};

    const int arow = wave * 16 + m16;
#pragma unroll
    for (int kc = 0; kc < KC; ++kc) {
        h8 a = *(const h8*)&xls[arow * WS + kc * 32 + quad * 8];
#pragma unroll
        for (int t = 0; t < NT; ++t) {
            h8 b = *(const h8*)&wls[(t * 16 + m16) * WS + kc * 32 + quad * 8];
            acc[t] = __builtin_amdgcn_mfma_f32_16x16x32_f16(a, b, acc[t], 0, 0, 0);
        }
    }

    // epilogue: fold dis, repack via LDS (reuse xls), coalesced int4 stores
    float dsv[4];
    int   lrow[4];
#pragma unroll
    for (int reg = 0; reg < 4; ++reg) {
        lrow[reg] = wave * 16 + quad * 4 + reg;
        int grow  = row0 + lrow[reg];
        dsv[reg]  = (grow < n) ? dis[grow] : 0.f;
    }
    __syncthreads();
    _Float16* stage = xls;
#pragma unroll
    for (int t = 0; t < NT; ++t) {
#pragma unroll
        for (int reg = 0; reg < 4; ++reg)
            stage[lrow[reg] * DOUT + t * 16 + m16] = (_Float16)(acc[t][reg] * dsv[reg]);
    }
    __syncthreads();
    for (int i = tid; i < 64 * DOUT / 8; i += 256) {
        int off = i * 8;
        int r = off / DOUT;
        if (row0 + r < n)
            *(int4*)&ys[(long)row0 * DOUT + off] = *(int4*)&stage[off];
    }
}

// ---------------- gather DOUT=64: 4 nodes/wave, 16 lanes x 8B, unroll 8, fp16 out ----------------
// out[d] = fp16( relu( dis[d] * (ys[d] + sum_edges ys[s]) + b ) )
// 32 random rows in flight per wave (4 nodes x unroll 8).

__device__ __forceinline__ void acc4(int2 w, float& a0, float& a1, float& a2, float& a3) {
    float2 lo = __half22float2(*(__half2*)&w.x);
    float2 hi = __half22float2(*(__half2*)&w.y);
    a0 += lo.x; a1 += lo.y; a2 += hi.x; a3 += hi.y;
}

__global__ void gather2h_kernel(const int* __restrict__ rowptr, const int* __restrict__ esrc,
                                const __half* __restrict__ ys, const float* __restrict__ dis,
                                const float* __restrict__ b, __half* __restrict__ out, int n) {
    const int node = blockIdx.x * 16 + (threadIdx.x >> 4);
    const int c = (threadIdx.x & 15) * 4;
    if (node >= n) return;

    int2 sw = *(const int2*)&ys[(long)node * 64 + c];
    float a0, a1, a2, a3;
    {
        float2 lo = __half22float2(*(__half2*)&sw.x);
        float2 hi = __half22float2(*(__half2*)&sw.y);
        a0 = lo.x; a1 = lo.y; a2 = hi.x; a3 = hi.y;   // self term (ys already dis-scaled)
    }

    int k = rowptr[node];
    const int end = rowptr[node + 1];
    for (; k + 8 <= end; k += 8) {
        int u0 = esrc[k], u1 = esrc[k + 1], u2 = esrc[k + 2], u3 = esrc[k + 3];
        int u4 = esrc[k + 4], u5 = esrc[k + 5], u6 = esrc[k + 6], u7 = esrc[k + 7];
        int2 w0 = *(const int2*)&ys[(long)u0 * 64 + c];
        int2 w1 = *(const int2*)&ys[(long)u1 * 64 + c];
        int2 w2 = *(const int2*)&ys[(long)u2 * 64 + c];
        int2 w3 = *(const int2*)&ys[(long)u3 * 64 + c];
        int2 w4 = *(const int2*)&ys[(long)u4 * 64 + c];
        int2 w5 = *(const int2*)&ys[(long)u5 * 64 + c];
        int2 w6 = *(const int2*)&ys[(long)u6 * 64 + c];
        int2 w7 = *(const int2*)&ys[(long)u7 * 64 + c];
        acc4(w0, a0, a1, a2, a3);
        acc4(w1, a0, a1, a2, a3);
        acc4(w2, a0, a1, a2, a3);
        acc4(w3, a0, a1, a2, a3);
        acc4(w4, a0, a1, a2, a3);
        acc4(w5, a0, a1, a2, a3);
        acc4(w6, a0, a1, a2, a3);
        acc4(w7, a0, a1, a2, a3);
    }
    for (; k < end; ++k) {
        int2 w = *(const int2*)&ys[(long)esrc[k] * 64 + c];
        acc4(w, a0, a1, a2, a3);
    }

    const float di = dis[node];
    a0 = fmaxf(a0 * di + b[c + 0], 0.0f);
    a1 = fmaxf(a1 * di + b[c + 1], 0.0f);
    a2 = fmaxf(a2 * di + b[c + 2], 0.0f);
    a3 = fmaxf(a3 * di + b[c + 3], 0.0f);
    __half2 h0 = __halves2half2(__float2half(a0), __float2half(a1));
    __half2 h1 = __halves2half2(__float2half(a2), __float2half(a3));
    int2 o;
    o.x = *(int*)&h0;
    o.y = *(int*)&h1;
    *(int2*)&out[(long)node * 64 + c] = o;
}

// ---------------- gather DOUT=32: 8 nodes/wave, 8 lanes x 8B, unroll 8, fp32 out ----------------

__global__ void gather4h_kernel(const int* __restrict__ rowptr, const int* __restrict__ esrc,
                                const __half* __restrict__ ys, const float* __restrict__ dis,
                                const float* __restrict__ b, float* __restrict__ out, int n) {
    const int node = blockIdx.x * 32 + (threadIdx.x >> 3);
    const int c = (threadIdx.x & 7) * 4;
    if (node >= n) return;

    int2 sw = *(const int2*)&ys[(long)node * 32 + c];
    float a0, a1, a2, a3;
    {
        float2 lo = __half22float2(*(__half2*)&sw.x);
        float2 hi = __half22float2(*(__half2*)&sw.y);
        a0 = lo.x; a1 = lo.y; a2 = hi.x; a3 = hi.y;
    }

    int k = rowptr[node];
    const int end = rowptr[node + 1];
    for (; k + 8 <= end; k += 8) {
        int u0 = esrc[k], u1 = esrc[k + 1], u2 = esrc[k + 2], u3 = esrc[k + 3];
        int u4 = esrc[k + 4], u5 = esrc[k + 5], u6 = esrc[k + 6], u7 = esrc[k + 7];
        int2 w0 = *(const int2*)&ys[(long)u0 * 32 + c];
        int2 w1 = *(const int2*)&ys[(long)u1 * 32 + c];
        int2 w2 = *(const int2*)&ys[(long)u2 * 32 + c];
        int2 w3 = *(const int2*)&ys[(long)u3 * 32 + c];
        int2 w4 = *(const int2*)&ys[(long)u4 * 32 + c];
        int2 w5 = *(const int2*)&ys[(long)u5 * 32 + c];
        int2 w6 = *(const int2*)&ys[(long)u6 * 32 + c];
        int2 w7 = *(const int2*)&ys[(long)u7 * 32 + c];
        acc4(w0, a0, a1, a2, a3);
        acc4(w1, a0, a1, a2, a3);
        acc4(w2, a0, a1, a2, a3);
        acc4(w3, a0, a1, a2, a3);
        acc4(w4, a0, a1, a2, a3);
        acc4(w5, a0, a1, a2, a3);
        acc4(w6, a0, a1, a2, a3);
        acc4(w7, a0, a1, a2, a3);
    }
    for (; k < end; ++k) {
        int2 w = *(const int2*)&ys[(long)esrc[k] * 32 + c];
        acc4(w, a0, a1, a2, a3);
    }

    const float di = dis[node];
    float4 o;
    o.x = a0 * di + b[c + 0];
    o.y = a1 * di + b[c + 1];
    o.z = a2 * di + b[c + 2];
    o.w = a3 * di + b[c + 3];
    *(float4*)&out[(long)node * 32 + c] = o;
}

// ---------------- launch ----------------

extern "C" void kernel_launch(void* const* d_in, const int* in_sizes, int n_in,
                              void* d_out, int out_size, void* d_ws, size_t ws_size,
                              hipStream_t stream) {
    const float* features = (const float*)d_in[0];
    const int*   ei       = (const int*)d_in[1];
    const float* W0 = (const float*)d_in[2];
    const float* b0 = (const float*)d_in[3];
    const float* W1 = (const float*)d_in[4];
    const float* b1 = (const float*)d_in[5];
    const float* W2 = (const float*)d_in[6];
    const float* b2 = (const float*)d_in[7];

    const int* src = ei;             // edge_index[0]
    const int* dst = ei + N_EDGES;   // edge_index[1]

    const int n = N_NODES;

    // workspace layout (int slots)
    int*    H      = (int*)d_ws;                       // [0, 131072)
    int*    btot   = (int*)d_ws + 131072;              // [131072, 132096)
    int*    bbase  = (int*)d_ws + 132096;              // [132096, 133120)
    int*    bptr   = (int*)d_ws + 133120;              // [133120, 135168)
    float*  dis    = (float*)d_ws + 135168;            // [135168, 266240)
    int*    rowptr = (int*)d_ws + 266240;              // [266240, 397312)  n+1 fits
    int*    tmp    = (int*)d_ws + 397312;              // E ints
    int*    esrc   = (int*)d_ws + 1997312;             // E ints
    __half* ys     = (__half*)((int*)d_ws + 3597312);  // N*64 halves = 3.2M ints
    __half* act    = (__half*)((int*)d_ws + 6797312);  // N*64 halves = 3.2M ints
    __half* wt0    = (__half*)((int*)d_ws + 13197312); // 8192 halves
    __half* wt1    = (__half*)((int*)d_ws + 13201408); // 4096 halves
    __half* wt2    = (__half*)((int*)d_ws + 13203456); // 2048 halves
    float*  outf   = (float*)d_out;                    // N*32 fp32

    // ---- contention-free CSR build + transposes ----
    hist_kernel<<<FBLK, 256, 0, stream>>>(dst, H);
    colscan_kernel<<<(NBK + 255) / 256, 256, 0, stream>>>(H, btot);
    bucketscan_kernel<<<1, 1024, 0, stream>>>(btot, bbase, bptr);
    binfill_kernel<<<FBLK, 256, 0, stream>>>(src, dst, H, bbase, tmp);
    bucketfin_kernel<<<NBK, 256, 0, stream>>>(tmp, bptr, esrc, rowptr, dis, n);
    transpose_all_kernel<<<56, 256, 0, stream>>>(W0, W1, W2, wt0, wt1, wt2);

    // ---- layer 0: 128 -> 64, ReLU ----
    gemm_kernel<float, 128, 64><<<(n + 63) / 64, 256, 0, stream>>>(features, wt0, dis, ys, n);
    gather2h_kernel<<<(n + 15) / 16, 256, 0, stream>>>(rowptr, esrc, ys, dis, b0, act, n);

    // ---- layer 1: 64 -> 64, ReLU ----
    gemm_kernel<__half, 64, 64><<<(n + 63) / 64, 256, 0, stream>>>(act, wt1, dis, ys, n);
    gather2h_kernel<<<(n + 15) / 16, 256, 0, stream>>>(rowptr, esrc, ys, dis, b1, act, n);

    // ---- layer 2: 64 -> 32, no ReLU ----
    gemm_kernel<__half, 64, 32><<<(n + 63) / 64, 256, 0, stream>>>(act, wt2, dis, ys, n);
    gather4h_kernel<<<(n + 31) / 32, 256, 0, stream>>>(rowptr, esrc, ys, dis, b2, outf, n);
}